// Round 34
// baseline (62.639 us; speedup 1.0000x reference)
//
#include <hip/hip_runtime.h>
#include <hip/hip_bf16.h>
#include <cstdint>

// MoE MLP fused forward. T=512, K=2 slots, E=32, H=512, I=512 (2I=1024).
// DEVICE DTYPES (probe-verified r20-r22): f32 tensors with bf16-exact values;
// output = full 262144 x f32 at d_out.
//
// r31 59.3us (glds, kz=4 partials, verified). r33 fused-K FAILED (0.605):
// staged 32-row A-tiles but MFMA A-frag reads rows n16=0..15 only; acc1 was
// mapped to g0+32 instead of row 16+n16 -> tokens 16..31/48..63 never
// computed. r34 = r33's fusion with r31's VERIFIED geometry: group g0+=32,
// one 32-row A-tile, acc0<-rows n16, acc1<-rows 16+n16, epilogue
// mrow = g0 + tile*16 + k8*4 + q. Full-K loop-carried acc (no partial
// buffers), swiglu fused in mlp1 epilogue (shfl_xor, r26-verified), bf16
// hbuf, 4 launches, no atomics -> bitwise deterministic.

#define MOE_E 32
#define MOE_H 512
#define MOE_I 512
#define MOE_2I 1024
#define MOE_CAP 1024

typedef __attribute__((ext_vector_type(8))) short s16x8;   // 8 bf16
typedef __attribute__((ext_vector_type(4))) float f32x4;   // 4 f32 acc
typedef unsigned short u16;

#define GLDS16(g, l)  __builtin_amdgcn_global_load_lds(                        \
    (const __attribute__((address_space(1))) unsigned int*)(g),                \
    (__attribute__((address_space(3))) unsigned int*)(l), 16, 0, 0)

__device__ __forceinline__ s16x8 pack8(float4 f0, float4 f1) {
    union { unsigned int u[4]; s16x8 v; } r;
    r.u[0] = (__float_as_uint(f0.y) & 0xFFFF0000u) | (__float_as_uint(f0.x) >> 16);
    r.u[1] = (__float_as_uint(f0.w) & 0xFFFF0000u) | (__float_as_uint(f0.z) >> 16);
    r.u[2] = (__float_as_uint(f1.y) & 0xFFFF0000u) | (__float_as_uint(f1.x) >> 16);
    r.u[3] = (__float_as_uint(f1.w) & 0xFFFF0000u) | (__float_as_uint(f1.z) >> 16);
    return r.v;
}

__device__ __forceinline__ u16 f2bf_rtne(float f) {
    const unsigned int u = __float_as_uint(f);
    return (u16)((u + 0x7FFFu + ((u >> 16) & 1u)) >> 16);
}

// ---------------- route: bucket (token,slot) pairs by expert ----------------
__global__ __launch_bounds__(1024) void moe_route(const int* __restrict__ idx,
                                                  int* __restrict__ cnt,
                                                  int* __restrict__ lists) {
    __shared__ int scnt[MOE_E];
    const int p = threadIdx.x;
    if (p < MOE_E) scnt[p] = 0;
    __syncthreads();
    int e = idx[p];
    e = (e < 0) ? 0 : (e > MOE_E - 1 ? MOE_E - 1 : e);
    const int pos = atomicAdd(&scnt[e], 1);
    lists[e * MOE_CAP + pos] = p;
    __syncthreads();
    if (p < MOE_E) cnt[p] = scnt[p];
}

// ---- mlp1 + swiglu (MFMA, glds, full-K): grid (16, E), 256 thr. ----
// Block: 64 w1-rows; 32-token group; K-loop 4 chunks of 128 (Bs restaged).
// LDS 48KB: Bs units [32q][64r] f32, As units [32q][32r] f32.
// acc0 <- token rows n16, acc1 <- rows 16+n16 (r31-verified mapping).
// Epilogue: bias + shfl_xor swiglu -> hbuf bf16 (h col = cg>>1).
__global__ __launch_bounds__(256) void moe_mlp1(
    const float* __restrict__ x, const float* __restrict__ w1,
    const float* __restrict__ b1, const int* __restrict__ cnt,
    const int* __restrict__ lists, u16* __restrict__ hbuf) {
    __shared__ float Bs[2048 * 4];   // 32 KB
    __shared__ float As[1024 * 4];   // 16 KB
    const int e = blockIdx.y;
    const int ne = cnt[e];
    if (ne == 0) return;
    const int tid  = threadIdx.x;
    const int lane = tid & 63;
    const int wave = tid >> 6;
    const int n16  = lane & 15;
    const int k8   = lane >> 4;
    const int* lst = lists + e * MOE_CAP;
    const int cg = blockIdx.x * 64 + wave * 16 + n16;      // w1 row 0..1023
    const float bv = b1[e * MOE_2I + cg];
    const float* wbase = w1 + ((size_t)e * MOE_2I + blockIdx.x * 64) * MOE_H;

    for (int g0 = 0; g0 < ne; g0 += 32) {
        f32x4 acc0 = {0.f, 0.f, 0.f, 0.f};   // token rows n16
        f32x4 acc1 = {0.f, 0.f, 0.f, 0.f};   // token rows 16+n16
        for (int kc = 0; kc < 4; ++kc) {
            __syncthreads();   // prior chunk's LDS readers done
            // Bs: 2048 units (u = q*64 + r), 8 glds/thread
            #pragma unroll
            for (int j = 0; j < 8; ++j) {
                const int u = (j * 4 + wave) * 64 + lane;
                const int q = u >> 6, r = u & 63;
                GLDS16(wbase + (size_t)r * MOE_H + kc * 128 + q * 4,
                       Bs + (size_t)(j * 4 + wave) * 256);
            }
            // As: 1024 units (u = q*32 + r), 4 glds/thread
            #pragma unroll
            for (int j = 0; j < 4; ++j) {
                const int u = (j * 4 + wave) * 64 + lane;
                const int q = u >> 5, r = u & 31;
                const int pm = lst[min(g0 + r, ne - 1)];
                GLDS16(x + (size_t)(pm >> 1) * MOE_H + kc * 128 + q * 4,
                       As + (size_t)(j * 4 + wave) * 256);
            }
            __syncthreads();   // vmcnt drain + barrier: tiles visible

            #pragma unroll
            for (int ks = 0; ks < 4; ++ks) {
                const int qB = ks * 8 + k8 * 2;
                const float4 B0 = *(const float4*)(Bs + 4 * (qB * 64 + wave * 16 + n16));
                const float4 B1 = *(const float4*)(Bs + 4 * ((qB + 1) * 64 + wave * 16 + n16));
                const s16x8 BF = pack8(B0, B1);
                const float4 A00 = *(const float4*)(As + 4 * (qB * 32 + n16));
                const float4 A01 = *(const float4*)(As + 4 * ((qB + 1) * 32 + n16));
                acc0 = __builtin_amdgcn_mfma_f32_16x16x32_bf16(pack8(A00, A01), BF, acc0, 0, 0, 0);
                const float4 A10 = *(const float4*)(As + 4 * (qB * 32 + 16 + n16));
                const float4 A11 = *(const float4*)(As + 4 * ((qB + 1) * 32 + 16 + n16));
                acc1 = __builtin_amdgcn_mfma_f32_16x16x32_bf16(pack8(A10, A11), BF, acc1, 0, 0, 0);
            }
        }
        // ---- epilogue: bias + swiglu (even cg = gate, odd = linear) ----
        #pragma unroll
        for (int tile = 0; tile < 2; ++tile) {
            const f32x4 acc = tile ? acc1 : acc0;
            #pragma unroll
            for (int q = 0; q < 4; ++q) {
                const float val = acc[q] + bv;
                const float other = __shfl_xor(val, 1);   // partner column
                const int mrow = g0 + tile * 16 + k8 * 4 + q;  // D: row=(l>>4)*4+q
                if ((cg & 1) == 0 && mrow < ne) {
                    const float g = fminf(val, 7.0f);
                    const float l = fminf(fmaxf(other, -7.0f), 7.0f);
                    const float h = g / (1.0f + expf(-1.702f * g)) * (l + 1.0f);
                    const int p = lst[mrow];
                    hbuf[(size_t)p * MOE_I + (cg >> 1)] = f2bf_rtne(h);
                }
            }
        }
    }
}

// ---- mlp2 (MFMA, glds, full-K): grid (8, E). A = hbuf bf16. ----
// LDS 40KB: Bs f32 [32q][64r], As bf16 units [16q][32r] (8KB).
__global__ __launch_bounds__(256) void moe_mlp2(
    const u16* __restrict__ hbuf, const float* __restrict__ w2,
    const float* __restrict__ b2, const int* __restrict__ cnt,
    const int* __restrict__ lists, float* __restrict__ po) {
    __shared__ float Bs[2048 * 4];   // 32 KB
    __shared__ u16 As[512 * 8];      // 8 KB: unit u = q*32+r, 8 bf16
    const int e = blockIdx.y;
    const int ne = cnt[e];
    if (ne == 0) return;
    const int tid  = threadIdx.x;
    const int lane = tid & 63;
    const int wave = tid >> 6;
    const int n16  = lane & 15;
    const int k8   = lane >> 4;
    const int* lst = lists + e * MOE_CAP;
    const int c = blockIdx.x * 64 + wave * 16 + n16;       // out col 0..511
    const float bv = b2[e * MOE_H + c];
    const float* wbase = w2 + ((size_t)e * MOE_H + blockIdx.x * 64) * MOE_I;

    for (int g0 = 0; g0 < ne; g0 += 32) {
        f32x4 acc0 = {0.f, 0.f, 0.f, 0.f};
        f32x4 acc1 = {0.f, 0.f, 0.f, 0.f};
        for (int kc = 0; kc < 4; ++kc) {
            __syncthreads();
            #pragma unroll
            for (int j = 0; j < 8; ++j) {
                const int u = (j * 4 + wave) * 64 + lane;
                const int q = u >> 6, r = u & 63;
                GLDS16(wbase + (size_t)r * MOE_I + kc * 128 + q * 4,
                       Bs + (size_t)(j * 4 + wave) * 256);
            }
            // As bf16: 512 units (u = q*32+r, q=0..15), 2 glds/thread
            #pragma unroll
            for (int j = 0; j < 2; ++j) {
                const int u = (j * 4 + wave) * 64 + lane;
                const int q = u >> 5, r = u & 31;
                const int pm = lst[min(g0 + r, ne - 1)];
                GLDS16(hbuf + (size_t)pm * MOE_I + kc * 128 + q * 8,
                       As + (size_t)(j * 4 + wave) * 512);
            }
            __syncthreads();

            #pragma unroll
            for (int ks = 0; ks < 4; ++ks) {
                const int qB = ks * 8 + k8 * 2;
                const float4 B0 = *(const float4*)(Bs + 4 * (qB * 64 + wave * 16 + n16));
                const float4 B1 = *(const float4*)(Bs + 4 * ((qB + 1) * 64 + wave * 16 + n16));
                const s16x8 BF = pack8(B0, B1);
                const int uA = (ks * 4 + k8) * 32;         // bf16 unit row base
                const s16x8 A0 = *(const s16x8*)(As + (size_t)(uA + n16) * 8);
                const s16x8 A1 = *(const s16x8*)(As + (size_t)(uA + 16 + n16) * 8);
                acc0 = __builtin_amdgcn_mfma_f32_16x16x32_bf16(A0, BF, acc0, 0, 0, 0);
                acc1 = __builtin_amdgcn_mfma_f32_16x16x32_bf16(A1, BF, acc1, 0, 0, 0);
            }
        }
        #pragma unroll
        for (int tile = 0; tile < 2; ++tile) {
            const f32x4 acc = tile ? acc1 : acc0;
            #pragma unroll
            for (int q = 0; q < 4; ++q) {
                const int mrow = g0 + tile * 16 + k8 * 4 + q;
                if (mrow < ne) {
                    const int p = lst[mrow];
                    po[(size_t)p * MOE_H + c] = acc[q] + bv;
                }
            }
        }
    }
}

// ---- combine: out[t,c] = ew0*po[2t,c] + ew1*po[2t+1,c] ----
__global__ __launch_bounds__(256) void MoEMLPFused_74191265071207_kernel(
    const float* __restrict__ po, const float* __restrict__ ew,
    float* __restrict__ out) {
    const int o = blockIdx.x * 256 + threadIdx.x;   // < 262144
    const int t = o >> 9;
    const int c = o & 511;
    out[o] = ew[2 * t + 0] * po[(size_t)(2 * t + 0) * MOE_H + c]
           + ew[2 * t + 1] * po[(size_t)(2 * t + 1) * MOE_H + c];
}

extern "C" void kernel_launch(void* const* d_in, const int* in_sizes, int n_in,
                              void* d_out, int out_size, void* d_ws, size_t ws_size,
                              hipStream_t stream) {
    const float* x   = (const float*)d_in[0];
    const int*   idx = (const int*)d_in[1];
    const float* ew  = (const float*)d_in[2];
    const float* w1  = (const float*)d_in[3];
    const float* b1  = (const float*)d_in[4];
    const float* w2  = (const float*)d_in[5];
    const float* b2  = (const float*)d_in[6];
    float* out = (float*)d_out;

    // ws: cnt 256B | lists 128KB | hbuf bf16 1MB | po f32 2MB  (~3.2MB)
    char* ws = (char*)d_ws;
    int* cnt   = (int*)ws;
    int* lists = (int*)(ws + 256);
    u16* hbuf  = (u16*)(ws + 256 + MOE_E * MOE_CAP * 4);
    float* po  = (float*)((char*)hbuf + (size_t)MOE_CAP * MOE_I * 2);

    moe_route<<<1, 1024, 0, stream>>>(idx, cnt, lists);
    moe_mlp1<<<dim3(16, MOE_E), 256, 0, stream>>>(x, w1, b1, cnt, lists, hbuf);
    moe_mlp2<<<dim3(8, MOE_E), 256, 0, stream>>>(hbuf, w2, b2, cnt, lists, po);
    MoEMLPFused_74191265071207_kernel<<<(512 * MOE_H) / 256, 256, 0, stream>>>(
        po, ew, out);
}

// Round 35
// 51.148 us; speedup vs baseline: 1.2247x; 1.2247x over previous
//
#include <hip/hip_runtime.h>
#include <hip/hip_bf16.h>
#include <cstdint>

// MoE MLP fused forward. T=512, K=2 slots, E=32, H=512, I=512 (2I=1024).
// DEVICE DTYPES (probe-verified r20-r22): f32 tensors with bf16-exact values;
// output = full 262144 x f32 at d_out.
//
// r34: PASS 62.6us; mlp1 40us @ 1.39 TB/s. Diagnosis across r30/r31/r34:
// glds gave load DEPTH but my unit-interleaved LDS layout made each staging
// instruction read 64 x 16B segments at 2KB stride (HBM scatter, ~1/5 rate);
// r30 had sequential pattern but no depth. r35: BOTH — row-major LDS tiles
// (1 instr = 2 contiguous 512B row-chunks) with XOR-swizzle (unit ^= row&7)
// applied to the per-lane GLOBAL source (write) and the ds_read slot (read)
// per guide rule #21; fragment reads spread 8 bank-groups (2-way, free).
// Geometry identical to r34 (verified). 4 launches, no atomics ->
// bitwise deterministic.

#define MOE_E 32
#define MOE_H 512
#define MOE_I 512
#define MOE_2I 1024
#define MOE_CAP 1024

typedef __attribute__((ext_vector_type(8))) short s16x8;   // 8 bf16
typedef __attribute__((ext_vector_type(4))) float f32x4;   // 4 f32 acc
typedef unsigned short u16;

#define GLDS16(g, l)  __builtin_amdgcn_global_load_lds(                        \
    (const __attribute__((address_space(1))) unsigned int*)(g),                \
    (__attribute__((address_space(3))) unsigned int*)(l), 16, 0, 0)

__device__ __forceinline__ s16x8 pack8(float4 f0, float4 f1) {
    union { unsigned int u[4]; s16x8 v; } r;
    r.u[0] = (__float_as_uint(f0.y) & 0xFFFF0000u) | (__float_as_uint(f0.x) >> 16);
    r.u[1] = (__float_as_uint(f0.w) & 0xFFFF0000u) | (__float_as_uint(f0.z) >> 16);
    r.u[2] = (__float_as_uint(f1.y) & 0xFFFF0000u) | (__float_as_uint(f1.x) >> 16);
    r.u[3] = (__float_as_uint(f1.w) & 0xFFFF0000u) | (__float_as_uint(f1.z) >> 16);
    return r.v;
}

__device__ __forceinline__ u16 f2bf_rtne(float f) {
    const unsigned int u = __float_as_uint(f);
    return (u16)((u + 0x7FFFu + ((u >> 16) & 1u)) >> 16);
}

// ---------------- route: bucket (token,slot) pairs by expert ----------------
__global__ __launch_bounds__(1024) void moe_route(const int* __restrict__ idx,
                                                  int* __restrict__ cnt,
                                                  int* __restrict__ lists) {
    __shared__ int scnt[MOE_E];
    const int p = threadIdx.x;
    if (p < MOE_E) scnt[p] = 0;
    __syncthreads();
    int e = idx[p];
    e = (e < 0) ? 0 : (e > MOE_E - 1 ? MOE_E - 1 : e);
    const int pos = atomicAdd(&scnt[e], 1);
    lists[e * MOE_CAP + pos] = p;
    __syncthreads();
    if (p < MOE_E) cnt[p] = scnt[p];
}

// ---- mlp1 + swiglu (MFMA, glds, full-K): grid (16, E), 256 thr. ----
// Tiles: Bs row-major [64r][32 units], As [32r][32 units] (16B units,
// unit index XOR (row&7)). Staging: 1 instr = 2 contiguous 512B row-chunks.
// acc0 <- token rows n16, acc1 <- rows 16+n16. Epilogue: bias + shfl_xor
// swiglu -> hbuf bf16 (h col = cg>>1). (r34-verified geometry.)
__global__ __launch_bounds__(256) void moe_mlp1(
    const float* __restrict__ x, const float* __restrict__ w1,
    const float* __restrict__ b1, const int* __restrict__ cnt,
    const int* __restrict__ lists, u16* __restrict__ hbuf) {
    __shared__ float Bs[2048 * 4];   // 32 KB
    __shared__ float As[1024 * 4];   // 16 KB
    const int e = blockIdx.y;
    const int ne = cnt[e];
    if (ne == 0) return;
    const int tid  = threadIdx.x;
    const int lane = tid & 63;
    const int wave = tid >> 6;
    const int n16  = lane & 15;
    const int k8   = lane >> 4;
    const int* lst = lists + e * MOE_CAP;
    const int cg = blockIdx.x * 64 + wave * 16 + n16;      // w1 row 0..1023
    const float bv = b1[e * MOE_2I + cg];
    const float* wbase = w1 + ((size_t)e * MOE_2I + blockIdx.x * 64) * MOE_H;

    for (int g0 = 0; g0 < ne; g0 += 32) {
        f32x4 acc0 = {0.f, 0.f, 0.f, 0.f};   // token rows n16
        f32x4 acc1 = {0.f, 0.f, 0.f, 0.f};   // token rows 16+n16
        for (int kc = 0; kc < 4; ++kc) {
            __syncthreads();   // prior chunk's LDS readers done
            // Bs: slot u (16B) = r*32 + (c^(r&7)); global = row r, unit c.
            // Per instr: lanes 0-31 row r (contiguous 512B permuted), 32-63 r+1.
            #pragma unroll
            for (int j = 0; j < 8; ++j) {
                const int u = (j * 4 + wave) * 64 + lane;
                const int r = u >> 5;          // 0..63
                const int c = u & 31;          // stored unit -> global unit c^(r&7)
                GLDS16(wbase + (size_t)r * MOE_H + kc * 128 + 4 * (c ^ (r & 7)),
                       Bs + (size_t)(j * 4 + wave) * 256);
            }
            // As: slot u = r*32 + (c^(r&7)), r = token row 0..31.
            #pragma unroll
            for (int j = 0; j < 4; ++j) {
                const int u = (j * 4 + wave) * 64 + lane;
                const int r = u >> 5;          // 0..31
                const int c = u & 31;
                const int pm = lst[min(g0 + r, ne - 1)];
                GLDS16(x + (size_t)(pm >> 1) * MOE_H + kc * 128 + 4 * (c ^ (r & 7)),
                       As + (size_t)(j * 4 + wave) * 256);
            }
            __syncthreads();   // vmcnt drain + barrier: tiles visible

            #pragma unroll
            for (int ks = 0; ks < 4; ++ks) {
                const int c0 = ks * 8 + k8 * 2;            // even unit index
                const int Rb = wave * 16 + n16;
                const float4 B0 = *(const float4*)(Bs + 4 * (Rb * 32 + ((c0    ) ^ (Rb & 7))));
                const float4 B1 = *(const float4*)(Bs + 4 * (Rb * 32 + ((c0 + 1) ^ (Rb & 7))));
                const s16x8 BF = pack8(B0, B1);
                const int Ra0 = n16;
                const float4 A00 = *(const float4*)(As + 4 * (Ra0 * 32 + ((c0    ) ^ (Ra0 & 7))));
                const float4 A01 = *(const float4*)(As + 4 * (Ra0 * 32 + ((c0 + 1) ^ (Ra0 & 7))));
                acc0 = __builtin_amdgcn_mfma_f32_16x16x32_bf16(pack8(A00, A01), BF, acc0, 0, 0, 0);
                const int Ra1 = 16 + n16;
                const float4 A10 = *(const float4*)(As + 4 * (Ra1 * 32 + ((c0    ) ^ (Ra1 & 7))));
                const float4 A11 = *(const float4*)(As + 4 * (Ra1 * 32 + ((c0 + 1) ^ (Ra1 & 7))));
                acc1 = __builtin_amdgcn_mfma_f32_16x16x32_bf16(pack8(A10, A11), BF, acc1, 0, 0, 0);
            }
        }
        // ---- epilogue: bias + swiglu (even cg = gate, odd = linear) ----
        #pragma unroll
        for (int tile = 0; tile < 2; ++tile) {
            const f32x4 acc = tile ? acc1 : acc0;
            #pragma unroll
            for (int q = 0; q < 4; ++q) {
                const float val = acc[q] + bv;
                const float other = __shfl_xor(val, 1);   // partner column
                const int mrow = g0 + tile * 16 + k8 * 4 + q;  // D: row=(l>>4)*4+q
                if ((cg & 1) == 0 && mrow < ne) {
                    const float g = fminf(val, 7.0f);
                    const float l = fminf(fmaxf(other, -7.0f), 7.0f);
                    const float h = g / (1.0f + expf(-1.702f * g)) * (l + 1.0f);
                    const int p = lst[mrow];
                    hbuf[(size_t)p * MOE_I + (cg >> 1)] = f2bf_rtne(h);
                }
            }
        }
    }
}

// ---- mlp2 (MFMA, glds, full-K): grid (8, E). A = hbuf bf16. ----
// Bs as mlp1. As bf16 row-major [32r][16 units], unit XOR (row&7).
__global__ __launch_bounds__(256) void moe_mlp2(
    const u16* __restrict__ hbuf, const float* __restrict__ w2,
    const float* __restrict__ b2, const int* __restrict__ cnt,
    const int* __restrict__ lists, float* __restrict__ po) {
    __shared__ float Bs[2048 * 4];   // 32 KB
    __shared__ u16 As[512 * 8];      // 8 KB
    const int e = blockIdx.y;
    const int ne = cnt[e];
    if (ne == 0) return;
    const int tid  = threadIdx.x;
    const int lane = tid & 63;
    const int wave = tid >> 6;
    const int n16  = lane & 15;
    const int k8   = lane >> 4;
    const int* lst = lists + e * MOE_CAP;
    const int c = blockIdx.x * 64 + wave * 16 + n16;       // out col 0..511
    const float bv = b2[e * MOE_H + c];
    const float* wbase = w2 + ((size_t)e * MOE_H + blockIdx.x * 64) * MOE_I;

    for (int g0 = 0; g0 < ne; g0 += 32) {
        f32x4 acc0 = {0.f, 0.f, 0.f, 0.f};
        f32x4 acc1 = {0.f, 0.f, 0.f, 0.f};
        for (int kc = 0; kc < 4; ++kc) {
            __syncthreads();
            #pragma unroll
            for (int j = 0; j < 8; ++j) {
                const int u = (j * 4 + wave) * 64 + lane;
                const int r = u >> 5;
                const int cu = u & 31;
                GLDS16(wbase + (size_t)r * MOE_I + kc * 128 + 4 * (cu ^ (r & 7)),
                       Bs + (size_t)(j * 4 + wave) * 256);
            }
            // As bf16: slot u (16B) = r*16 + (cu^(r&7)), r = token row 0..31.
            #pragma unroll
            for (int j = 0; j < 2; ++j) {
                const int u = (j * 4 + wave) * 64 + lane;
                const int r = u >> 4;          // 0..31
                const int cu = u & 15;
                const int pm = lst[min(g0 + r, ne - 1)];
                GLDS16(hbuf + (size_t)pm * MOE_I + kc * 128 + 8 * (cu ^ (r & 7)),
                       As + (size_t)(j * 4 + wave) * 512);
            }
            __syncthreads();

            #pragma unroll
            for (int ks = 0; ks < 4; ++ks) {
                const int c0 = ks * 8 + k8 * 2;
                const int Rb = wave * 16 + n16;
                const float4 B0 = *(const float4*)(Bs + 4 * (Rb * 32 + ((c0    ) ^ (Rb & 7))));
                const float4 B1 = *(const float4*)(Bs + 4 * (Rb * 32 + ((c0 + 1) ^ (Rb & 7))));
                const s16x8 BF = pack8(B0, B1);
                const int cA = ks * 4 + k8;                // bf16 16B-unit index
                const int Ra0 = n16;
                const int Ra1 = 16 + n16;
                const s16x8 A0 = *(const s16x8*)(As + (size_t)(Ra0 * 16 + (cA ^ (Ra0 & 7))) * 8);
                const s16x8 A1 = *(const s16x8*)(As + (size_t)(Ra1 * 16 + (cA ^ (Ra1 & 7))) * 8);
                acc0 = __builtin_amdgcn_mfma_f32_16x16x32_bf16(A0, BF, acc0, 0, 0, 0);
                acc1 = __builtin_amdgcn_mfma_f32_16x16x32_bf16(A1, BF, acc1, 0, 0, 0);
            }
        }
        #pragma unroll
        for (int tile = 0; tile < 2; ++tile) {
            const f32x4 acc = tile ? acc1 : acc0;
            #pragma unroll
            for (int q = 0; q < 4; ++q) {
                const int mrow = g0 + tile * 16 + k8 * 4 + q;
                if (mrow < ne) {
                    const int p = lst[mrow];
                    po[(size_t)p * MOE_H + c] = acc[q] + bv;
                }
            }
        }
    }
}

// ---- combine: out[t,c] = ew0*po[2t,c] + ew1*po[2t+1,c] ----
__global__ __launch_bounds__(256) void MoEMLPFused_74191265071207_kernel(
    const float* __restrict__ po, const float* __restrict__ ew,
    float* __restrict__ out) {
    const int o = blockIdx.x * 256 + threadIdx.x;   // < 262144
    const int t = o >> 9;
    const int c = o & 511;
    out[o] = ew[2 * t + 0] * po[(size_t)(2 * t + 0) * MOE_H + c]
           + ew[2 * t + 1] * po[(size_t)(2 * t + 1) * MOE_H + c];
}

extern "C" void kernel_launch(void* const* d_in, const int* in_sizes, int n_in,
                              void* d_out, int out_size, void* d_ws, size_t ws_size,
                              hipStream_t stream) {
    const float* x   = (const float*)d_in[0];
    const int*   idx = (const int*)d_in[1];
    const float* ew  = (const float*)d_in[2];
    const float* w1  = (const float*)d_in[3];
    const float* b1  = (const float*)d_in[4];
    const float* w2  = (const float*)d_in[5];
    const float* b2  = (const float*)d_in[6];
    float* out = (float*)d_out;

    // ws: cnt 256B | lists 128KB | hbuf bf16 1MB | po f32 2MB  (~3.2MB)
    char* ws = (char*)d_ws;
    int* cnt   = (int*)ws;
    int* lists = (int*)(ws + 256);
    u16* hbuf  = (u16*)(ws + 256 + MOE_E * MOE_CAP * 4);
    float* po  = (float*)((char*)hbuf + (size_t)MOE_CAP * MOE_I * 2);

    moe_route<<<1, 1024, 0, stream>>>(idx, cnt, lists);
    moe_mlp1<<<dim3(16, MOE_E), 256, 0, stream>>>(x, w1, b1, cnt, lists, hbuf);
    moe_mlp2<<<dim3(8, MOE_E), 256, 0, stream>>>(hbuf, w2, b2, cnt, lists, po);
    MoEMLPFused_74191265071207_kernel<<<(512 * MOE_H) / 256, 256, 0, stream>>>(
        po, ew, out);
}

// Round 36
// 50.995 us; speedup vs baseline: 1.2283x; 1.0030x over previous
//
#include <hip/hip_runtime.h>
#include <hip/hip_bf16.h>
#include <cstdint>

// MoE MLP fused forward. T=512, K=2 slots, E=32, H=512, I=512 (2I=1024).
// DEVICE DTYPES (probe-verified r20-r22): f32 tensors with bf16-exact values;
// output = full 262144 x f32 at d_out.
//
// r35: 51.1us (row-major glds staging + XOR swizzle, verified). Remaining
// starvation: mlp1 8 waves/CU (2 blocks x 4 waves; Occ 14% in r34).
// r36: mlp1 -> 512-thread blocks (8 waves): wave w owns cols (w&3)*16,
// m-tile w>>2, ONE accumulator each — same tiles/swizzle/MFMA count, 2x
// waves/CU and 2x staging issue-parallelism. mlp2/combine unchanged
// (r35-verified). 4 launches, no atomics -> bitwise deterministic.

#define MOE_E 32
#define MOE_H 512
#define MOE_I 512
#define MOE_2I 1024
#define MOE_CAP 1024

typedef __attribute__((ext_vector_type(8))) short s16x8;   // 8 bf16
typedef __attribute__((ext_vector_type(4))) float f32x4;   // 4 f32 acc
typedef unsigned short u16;

#define GLDS16(g, l)  __builtin_amdgcn_global_load_lds(                        \
    (const __attribute__((address_space(1))) unsigned int*)(g),                \
    (__attribute__((address_space(3))) unsigned int*)(l), 16, 0, 0)

__device__ __forceinline__ s16x8 pack8(float4 f0, float4 f1) {
    union { unsigned int u[4]; s16x8 v; } r;
    r.u[0] = (__float_as_uint(f0.y) & 0xFFFF0000u) | (__float_as_uint(f0.x) >> 16);
    r.u[1] = (__float_as_uint(f0.w) & 0xFFFF0000u) | (__float_as_uint(f0.z) >> 16);
    r.u[2] = (__float_as_uint(f1.y) & 0xFFFF0000u) | (__float_as_uint(f1.x) >> 16);
    r.u[3] = (__float_as_uint(f1.w) & 0xFFFF0000u) | (__float_as_uint(f1.z) >> 16);
    return r.v;
}

__device__ __forceinline__ u16 f2bf_rtne(float f) {
    const unsigned int u = __float_as_uint(f);
    return (u16)((u + 0x7FFFu + ((u >> 16) & 1u)) >> 16);
}

// ---------------- route: bucket (token,slot) pairs by expert ----------------
__global__ __launch_bounds__(1024) void moe_route(const int* __restrict__ idx,
                                                  int* __restrict__ cnt,
                                                  int* __restrict__ lists) {
    __shared__ int scnt[MOE_E];
    const int p = threadIdx.x;
    if (p < MOE_E) scnt[p] = 0;
    __syncthreads();
    int e = idx[p];
    e = (e < 0) ? 0 : (e > MOE_E - 1 ? MOE_E - 1 : e);
    const int pos = atomicAdd(&scnt[e], 1);
    lists[e * MOE_CAP + pos] = p;
    __syncthreads();
    if (p < MOE_E) cnt[p] = scnt[p];
}

// ---- mlp1 + swiglu (MFMA, glds, full-K): grid (16, E), 512 thr = 8 waves. ----
// Wave w: cols (w&3)*16 + n16 within the 64-row block; m-tile w>>2 (token
// rows (w>>2)*16 + n16). Tiles: Bs row-major [64r][32u], As [32r][32u]
// (16B units, unit ^= row&7; write side permutes per-lane GLOBAL source).
// Epilogue: bias + shfl_xor swiglu -> hbuf bf16 (h col = cg>>1).
__global__ __launch_bounds__(512) void moe_mlp1(
    const float* __restrict__ x, const float* __restrict__ w1,
    const float* __restrict__ b1, const int* __restrict__ cnt,
    const int* __restrict__ lists, u16* __restrict__ hbuf) {
    __shared__ float Bs[2048 * 4];   // 32 KB
    __shared__ float As[1024 * 4];   // 16 KB
    const int e = blockIdx.y;
    const int ne = cnt[e];
    if (ne == 0) return;
    const int tid   = threadIdx.x;           // 0..511
    const int lane  = tid & 63;
    const int wave  = tid >> 6;              // 0..7
    const int n16   = lane & 15;
    const int k8    = lane >> 4;
    const int mtile = wave >> 2;             // 0..1
    const int* lst = lists + e * MOE_CAP;
    const int cg = blockIdx.x * 64 + (wave & 3) * 16 + n16;   // w1 row 0..1023
    const float bv = b1[e * MOE_2I + cg];
    const float* wbase = w1 + ((size_t)e * MOE_2I + blockIdx.x * 64) * MOE_H;

    for (int g0 = 0; g0 < ne; g0 += 32) {
        f32x4 acc = {0.f, 0.f, 0.f, 0.f};    // token rows mtile*16 + n16
        for (int kc = 0; kc < 4; ++kc) {
            __syncthreads();   // prior chunk's LDS readers done
            // Bs: 2048 units, 4 glds/thread. slot u = r*32 + (c^(r&7)).
            #pragma unroll
            for (int j = 0; j < 4; ++j) {
                const int u = (j * 8 + wave) * 64 + lane;
                const int r = u >> 5;          // 0..63
                const int c = u & 31;
                GLDS16(wbase + (size_t)r * MOE_H + kc * 128 + 4 * (c ^ (r & 7)),
                       Bs + (size_t)(j * 8 + wave) * 256);
            }
            // As: 1024 units, 2 glds/thread. r = token row 0..31.
            #pragma unroll
            for (int j = 0; j < 2; ++j) {
                const int u = (j * 8 + wave) * 64 + lane;
                const int r = u >> 5;          // 0..31
                const int c = u & 31;
                const int pm = lst[min(g0 + r, ne - 1)];
                GLDS16(x + (size_t)(pm >> 1) * MOE_H + kc * 128 + 4 * (c ^ (r & 7)),
                       As + (size_t)(j * 8 + wave) * 256);
            }
            __syncthreads();   // vmcnt drain + barrier: tiles visible

            #pragma unroll
            for (int ks = 0; ks < 4; ++ks) {
                const int c0 = ks * 8 + k8 * 2;            // even unit index
                const int Rb = (wave & 3) * 16 + n16;
                const float4 B0 = *(const float4*)(Bs + 4 * (Rb * 32 + ((c0    ) ^ (Rb & 7))));
                const float4 B1 = *(const float4*)(Bs + 4 * (Rb * 32 + ((c0 + 1) ^ (Rb & 7))));
                const int Ra = mtile * 16 + n16;
                const float4 A0 = *(const float4*)(As + 4 * (Ra * 32 + ((c0    ) ^ (Ra & 7))));
                const float4 A1 = *(const float4*)(As + 4 * (Ra * 32 + ((c0 + 1) ^ (Ra & 7))));
                acc = __builtin_amdgcn_mfma_f32_16x16x32_bf16(
                    pack8(A0, A1), pack8(B0, B1), acc, 0, 0, 0);
            }
        }
        // ---- epilogue: bias + swiglu (even cg = gate, odd = linear) ----
        #pragma unroll
        for (int q = 0; q < 4; ++q) {
            const float val = acc[q] + bv;
            const float other = __shfl_xor(val, 1);       // partner column
            const int mrow = g0 + mtile * 16 + k8 * 4 + q;  // D: row=(l>>4)*4+q
            if ((cg & 1) == 0 && mrow < ne) {
                const float g = fminf(val, 7.0f);
                const float l = fminf(fmaxf(other, -7.0f), 7.0f);
                const float h = g / (1.0f + expf(-1.702f * g)) * (l + 1.0f);
                const int p = lst[mrow];
                hbuf[(size_t)p * MOE_I + (cg >> 1)] = f2bf_rtne(h);
            }
        }
    }
}

// ---- mlp2 (MFMA, glds, full-K): grid (8, E), 256 thr. A = hbuf bf16. ----
// (r35-verified, unchanged.) Bs row-major swizzled; As bf16 [32r][16u].
__global__ __launch_bounds__(256) void moe_mlp2(
    const u16* __restrict__ hbuf, const float* __restrict__ w2,
    const float* __restrict__ b2, const int* __restrict__ cnt,
    const int* __restrict__ lists, float* __restrict__ po) {
    __shared__ float Bs[2048 * 4];   // 32 KB
    __shared__ u16 As[512 * 8];      // 8 KB
    const int e = blockIdx.y;
    const int ne = cnt[e];
    if (ne == 0) return;
    const int tid  = threadIdx.x;
    const int lane = tid & 63;
    const int wave = tid >> 6;
    const int n16  = lane & 15;
    const int k8   = lane >> 4;
    const int* lst = lists + e * MOE_CAP;
    const int c = blockIdx.x * 64 + wave * 16 + n16;       // out col 0..511
    const float bv = b2[e * MOE_H + c];
    const float* wbase = w2 + ((size_t)e * MOE_H + blockIdx.x * 64) * MOE_I;

    for (int g0 = 0; g0 < ne; g0 += 32) {
        f32x4 acc0 = {0.f, 0.f, 0.f, 0.f};
        f32x4 acc1 = {0.f, 0.f, 0.f, 0.f};
        for (int kc = 0; kc < 4; ++kc) {
            __syncthreads();
            #pragma unroll
            for (int j = 0; j < 8; ++j) {
                const int u = (j * 4 + wave) * 64 + lane;
                const int r = u >> 5;
                const int cu = u & 31;
                GLDS16(wbase + (size_t)r * MOE_I + kc * 128 + 4 * (cu ^ (r & 7)),
                       Bs + (size_t)(j * 4 + wave) * 256);
            }
            #pragma unroll
            for (int j = 0; j < 2; ++j) {
                const int u = (j * 4 + wave) * 64 + lane;
                const int r = u >> 4;          // 0..31
                const int cu = u & 15;
                const int pm = lst[min(g0 + r, ne - 1)];
                GLDS16(hbuf + (size_t)pm * MOE_I + kc * 128 + 8 * (cu ^ (r & 7)),
                       As + (size_t)(j * 4 + wave) * 512);
            }
            __syncthreads();

            #pragma unroll
            for (int ks = 0; ks < 4; ++ks) {
                const int c0 = ks * 8 + k8 * 2;
                const int Rb = wave * 16 + n16;
                const float4 B0 = *(const float4*)(Bs + 4 * (Rb * 32 + ((c0    ) ^ (Rb & 7))));
                const float4 B1 = *(const float4*)(Bs + 4 * (Rb * 32 + ((c0 + 1) ^ (Rb & 7))));
                const s16x8 BF = pack8(B0, B1);
                const int cA = ks * 4 + k8;                // bf16 16B-unit index
                const int Ra0 = n16;
                const int Ra1 = 16 + n16;
                const s16x8 A0 = *(const s16x8*)(As + (size_t)(Ra0 * 16 + (cA ^ (Ra0 & 7))) * 8);
                const s16x8 A1 = *(const s16x8*)(As + (size_t)(Ra1 * 16 + (cA ^ (Ra1 & 7))) * 8);
                acc0 = __builtin_amdgcn_mfma_f32_16x16x32_bf16(A0, BF, acc0, 0, 0, 0);
                acc1 = __builtin_amdgcn_mfma_f32_16x16x32_bf16(A1, BF, acc1, 0, 0, 0);
            }
        }
        #pragma unroll
        for (int tile = 0; tile < 2; ++tile) {
            const f32x4 acc = tile ? acc1 : acc0;
            #pragma unroll
            for (int q = 0; q < 4; ++q) {
                const int mrow = g0 + tile * 16 + k8 * 4 + q;
                if (mrow < ne) {
                    const int p = lst[mrow];
                    po[(size_t)p * MOE_H + c] = acc[q] + bv;
                }
            }
        }
    }
}

// ---- combine: out[t,c] = ew0*po[2t,c] + ew1*po[2t+1,c] ----
__global__ __launch_bounds__(256) void MoEMLPFused_74191265071207_kernel(
    const float* __restrict__ po, const float* __restrict__ ew,
    float* __restrict__ out) {
    const int o = blockIdx.x * 256 + threadIdx.x;   // < 262144
    const int t = o >> 9;
    const int c = o & 511;
    out[o] = ew[2 * t + 0] * po[(size_t)(2 * t + 0) * MOE_H + c]
           + ew[2 * t + 1] * po[(size_t)(2 * t + 1) * MOE_H + c];
}

extern "C" void kernel_launch(void* const* d_in, const int* in_sizes, int n_in,
                              void* d_out, int out_size, void* d_ws, size_t ws_size,
                              hipStream_t stream) {
    const float* x   = (const float*)d_in[0];
    const int*   idx = (const int*)d_in[1];
    const float* ew  = (const float*)d_in[2];
    const float* w1  = (const float*)d_in[3];
    const float* b1  = (const float*)d_in[4];
    const float* w2  = (const float*)d_in[5];
    const float* b2  = (const float*)d_in[6];
    float* out = (float*)d_out;

    // ws: cnt 256B | lists 128KB | hbuf bf16 1MB | po f32 2MB  (~3.2MB)
    char* ws = (char*)d_ws;
    int* cnt   = (int*)ws;
    int* lists = (int*)(ws + 256);
    u16* hbuf  = (u16*)(ws + 256 + MOE_E * MOE_CAP * 4);
    float* po  = (float*)((char*)hbuf + (size_t)MOE_CAP * MOE_I * 2);

    moe_route<<<1, 1024, 0, stream>>>(idx, cnt, lists);
    moe_mlp1<<<dim3(16, MOE_E), 512, 0, stream>>>(x, w1, b1, cnt, lists, hbuf);
    moe_mlp2<<<dim3(8, MOE_E), 256, 0, stream>>>(hbuf, w2, b2, cnt, lists, po);
    MoEMLPFused_74191265071207_kernel<<<(512 * MOE_H) / 256, 256, 0, stream>>>(
        po, ew, out);
}